// Round 6
// baseline (895.225 us; speedup 1.0000x reference)
//
#include <hip/hip_runtime.h>
#include <hip/hip_cooperative_groups.h>
#include <math.h>

namespace cg = cooperative_groups;

#define NT 256

typedef __attribute__((ext_vector_type(8))) short bf16x8;
typedef __attribute__((ext_vector_type(4))) float f32x4;

// ---------------- shared helpers ----------------

__device__ inline int detect_is64(const int* __restrict__ ei) {
    int is64 = 1;
#pragma unroll
    for (int k = 1; k < 16; k += 2) is64 &= (ei[k] == 0);
    return is64;
}

__device__ inline void cvt8(const float4& a, const float4& b, bf16x8& hi, bf16x8& lo) {
    float f[8] = {a.x, a.y, a.z, a.w, b.x, b.y, b.z, b.w};
#pragma unroll
    for (int j = 0; j < 8; j++) {
        unsigned u = __float_as_uint(f[j]);
        hi[j] = (short)(u >> 16);
        float fl = f[j] - __uint_as_float(u & 0xffff0000u);
        lo[j] = (short)(__float_as_uint(fl) >> 16);
    }
}

// =================================================================
// MEGA KERNEL: whole network in one cooperative launch.
// Grid 256 x 512 (1 block/CU, 8 waves). 18 grid.sync() phase barriers.
// =================================================================

__global__ __launch_bounds__(512, 1) void gat_mega(
    const float* __restrict__ x0, const int* __restrict__ ei, const int* __restrict__ nch,
    const float* __restrict__ Wl, const float* __restrict__ bl,
    const float* __restrict__ Wr, const float* __restrict__ br,
    const float* __restrict__ att, const float* __restrict__ bias,
    const float* __restrict__ wh, const float* __restrict__ bh,
    float* __restrict__ xl, float* __restrict__ xr,
    float* __restrict__ xA, float* __restrict__ xB,
    int* __restrict__ deg, int* __restrict__ off, int* __restrict__ cur,
    int* __restrict__ esrc, float* __restrict__ out,
    int out_n, int N, int E, int ntiles) {

    cg::grid_group grid = cg::this_grid();
    int t = threadIdx.x;
    int b = blockIdx.x;
    int wave = t >> 6, lane = t & 63;
    int gt = b * 512 + t;
    int gw = b * 8 + wave;
    const int GT = gridDim.x * 512;
    const int GW = gridDim.x * 8;
    int q = lane >> 4, cl = lane & 15;

    int is64 = detect_is64(ei);

    // ---- phase: zero deg ----
    for (int i = gt; i < N; i += GT) deg[i] = 0;
    grid.sync();

    // ---- phase: count ----
    for (int e = gt; e < E; e += GT) {
        long long pos = (long long)E + e;
        int d = ei[is64 ? 2 * pos : pos];
        if ((unsigned)d < (unsigned)N) atomicAdd(&deg[d], 1);
    }
    grid.sync();

    // ---- phase: scan (block 0 only) ----
    if (b == 0) {
        __shared__ int wsum[8];
        int per = (N + 511) >> 9;
        int b0 = t * per;
        int s = 0;
        for (int k = 0; k < per; k++) {
            int idx = b0 + k;
            if (idx < N) s += deg[idx];
        }
        int v = s;
#pragma unroll
        for (int o = 1; o < 64; o <<= 1) {
            int u = __shfl_up(v, o, 64);
            if (lane >= o) v += u;
        }
        if (lane == 63) wsum[wave] = v;
        __syncthreads();
        if (t == 0) {
            int r = 0;
#pragma unroll
            for (int j = 0; j < 8; j++) { int xx = wsum[j]; wsum[j] = r; r += xx; }
            off[N] = r;
        }
        __syncthreads();
        int run = v - s + wsum[wave];
        for (int k = 0; k < per; k++) {
            int idx = b0 + k;
            if (idx < N) {
                off[idx] = run;
                cur[idx] = run;
                run += deg[idx];
            }
        }
    }
    grid.sync();

    // ---- phase: fill ----
    for (int e = gt; e < E; e += GT) {
        long long spos = e, dpos = (long long)E + e;
        int s = ei[is64 ? 2 * spos : spos];
        int d = ei[is64 ? 2 * dpos : dpos];
        if ((unsigned)d >= (unsigned)N || (unsigned)s >= (unsigned)N) continue;
        int p = atomicAdd(&cur[d], 1);
        esrc[p] = s;
    }
    grid.sync();

    // ---- layers ----
    const float* xc = x0;
    float* xn = xA;
    for (int l = 0; l < 7; l++) {
        const float* WlL = Wl + (size_t)l * 16384;
        const float* WrL = Wr + (size_t)l * 16384;
        const float* blL = bl + (size_t)l * 128;
        const float* brL = br + (size_t)l * 128;

        // ===== GEMM phase: wave owns cols [32*wave, 32*wave+32) =====
        {
            bf16x8 Bh[2][4], Blo[2][4];
            float biasv[2];
            float* outp[2];
            int colc[2];
#pragma unroll
            for (int nt = 0; nt < 2; nt++) {
                int col = wave * 32 + nt * 16 + cl;
                const float* Wsrc;
                int cw;
                if (col < 128) { Wsrc = WlL; cw = col; biasv[nt] = blL[col]; outp[nt] = xl; colc[nt] = col; }
                else           { Wsrc = WrL; cw = col - 128; biasv[nt] = brL[cw]; outp[nt] = xr; colc[nt] = cw; }
#pragma unroll
                for (int kt = 0; kt < 4; kt++) {
                    int kb = kt * 32 + q * 8;
                    float ftmp[8];
#pragma unroll
                    for (int j = 0; j < 8; j++) ftmp[j] = Wsrc[(size_t)(kb + j) * 128 + cw];
                    float4 f0 = make_float4(ftmp[0], ftmp[1], ftmp[2], ftmp[3]);
                    float4 f1 = make_float4(ftmp[4], ftmp[5], ftmp[6], ftmp[7]);
                    cvt8(f0, f1, Bh[nt][kt], Blo[nt][kt]);
                }
            }

            int rt = b;
            if (rt < ntiles) {
                float4 curA[8], nxt[8];
                {
                    int row = rt * 16 + cl;
                    if (row >= N) row = N - 1;
                    const float* ap = xc + (size_t)row * 128 + q * 8;
#pragma unroll
                    for (int kt = 0; kt < 4; kt++) {
                        curA[2 * kt]     = *(const float4*)(ap + kt * 32);
                        curA[2 * kt + 1] = *(const float4*)(ap + kt * 32 + 4);
                    }
                }
                for (; rt < ntiles; rt += gridDim.x) {
                    int rn = rt + gridDim.x;
                    if (rn < ntiles) {
                        int row = rn * 16 + cl;
                        if (row >= N) row = N - 1;
                        const float* ap = xc + (size_t)row * 128 + q * 8;
#pragma unroll
                        for (int kt = 0; kt < 4; kt++) {
                            nxt[2 * kt]     = *(const float4*)(ap + kt * 32);
                            nxt[2 * kt + 1] = *(const float4*)(ap + kt * 32 + 4);
                        }
                    }
                    bf16x8 Ah[4], Al[4];
#pragma unroll
                    for (int kt = 0; kt < 4; kt++) cvt8(curA[2 * kt], curA[2 * kt + 1], Ah[kt], Al[kt]);

                    f32x4 acc0 = {0.f, 0.f, 0.f, 0.f}, acc1 = {0.f, 0.f, 0.f, 0.f};
#pragma unroll
                    for (int kt = 0; kt < 4; kt++) {
                        acc0 = __builtin_amdgcn_mfma_f32_16x16x32_bf16(Ah[kt], Bh[0][kt], acc0, 0, 0, 0);
                        acc1 = __builtin_amdgcn_mfma_f32_16x16x32_bf16(Ah[kt], Bh[1][kt], acc1, 0, 0, 0);
                        acc0 = __builtin_amdgcn_mfma_f32_16x16x32_bf16(Al[kt], Bh[0][kt], acc0, 0, 0, 0);
                        acc1 = __builtin_amdgcn_mfma_f32_16x16x32_bf16(Al[kt], Bh[1][kt], acc1, 0, 0, 0);
                        acc0 = __builtin_amdgcn_mfma_f32_16x16x32_bf16(Ah[kt], Blo[0][kt], acc0, 0, 0, 0);
                        acc1 = __builtin_amdgcn_mfma_f32_16x16x32_bf16(Ah[kt], Blo[1][kt], acc1, 0, 0, 0);
                    }
#pragma unroll
                    for (int nt = 0; nt < 2; nt++) {
                        f32x4 a = nt ? acc1 : acc0;
#pragma unroll
                        for (int r = 0; r < 4; r++) {
                            int row = rt * 16 + q * 4 + r;
                            if (row < N) outp[nt][(size_t)row * 128 + colc[nt]] = a[r] + biasv[nt];
                        }
                    }
#pragma unroll
                    for (int j = 0; j < 8; j++) curA[j] = nxt[j];
                }
            }
        }
        grid.sync();

        // ===== AGG phase: wave strides nodes; depth-2 value / depth-3 index prefetch =====
        {
            const float4* xl4 = (const float4*)xl;
            const float4* xr4 = (const float4*)xr;
            const float4* att4 = (const float4*)(att + (size_t)l * 128);
            const float4* bias4 = (const float4*)(bias + (size_t)l * 128);
            float4* out4 = (float4*)xn;
            int sub = lane >> 4;

            for (int i = gw; i < N; i += GW) {
                float4 xrA = xr4[(size_t)i * 32 + 2 * cl];
                float4 xrB = xr4[(size_t)i * 32 + 2 * cl + 1];
                float4 atA = att4[2 * cl];
                float4 atB = att4[2 * cl + 1];
                int start = off[i];
                int total = off[i + 1] - start + 1;   // + self-loop at slot 0
                int groups = (total + 3) >> 2;

                int k0 = sub;
                int s0 = (k0 < total) ? ((k0 == 0) ? i : esrc[start + k0 - 1]) : i;
                int k1 = 4 + sub;
                int s1 = (k1 < total) ? esrc[start + k1 - 1] : i;
                float4 v0A = xl4[(size_t)s0 * 32 + 2 * cl];
                float4 v0B = xl4[(size_t)s0 * 32 + 2 * cl + 1];
                int k2 = 8 + sub;
                int s2 = (k2 < total) ? esrc[start + k2 - 1] : i;
                float4 v1A = xl4[(size_t)s1 * 32 + 2 * cl];
                float4 v1B = xl4[(size_t)s1 * 32 + 2 * cl + 1];

                float s = 0.f;
                float4 aA = make_float4(0.f, 0.f, 0.f, 0.f);
                float4 aB = make_float4(0.f, 0.f, 0.f, 0.f);

                for (int g = 0; g < groups; g++) {
                    int k3 = 4 * (g + 3) + sub;
                    int s3 = (k3 < total) ? esrc[start + k3 - 1] : i;
                    float4 v2A = xl4[(size_t)s2 * 32 + 2 * cl];
                    float4 v2B = xl4[(size_t)s2 * 32 + 2 * cl + 1];

                    int kc = 4 * g + sub;
                    int valid = kc < total;
                    float z0 = v0A.x + xrA.x, z1 = v0A.y + xrA.y, z2 = v0A.z + xrA.z, z3 = v0A.w + xrA.w;
                    float z4 = v0B.x + xrB.x, z5 = v0B.y + xrB.y, z6 = v0B.z + xrB.z, z7 = v0B.w + xrB.w;
                    z0 = (z0 > 0.f) ? z0 : 0.2f * z0;
                    z1 = (z1 > 0.f) ? z1 : 0.2f * z1;
                    z2 = (z2 > 0.f) ? z2 : 0.2f * z2;
                    z3 = (z3 > 0.f) ? z3 : 0.2f * z3;
                    z4 = (z4 > 0.f) ? z4 : 0.2f * z4;
                    z5 = (z5 > 0.f) ? z5 : 0.2f * z5;
                    z6 = (z6 > 0.f) ? z6 : 0.2f * z6;
                    z7 = (z7 > 0.f) ? z7 : 0.2f * z7;
                    float p = z0 * atA.x + z1 * atA.y + z2 * atA.z + z3 * atA.w
                            + z4 * atB.x + z5 * atB.y + z6 * atB.z + z7 * atB.w;
                    p += __shfl_xor(p, 1, 64);
                    p = fminf(fmaxf(p, -80.f), 80.f);
                    float wgt = valid ? __expf(p) : 0.f;
                    s += wgt;
                    aA.x += wgt * v0A.x; aA.y += wgt * v0A.y; aA.z += wgt * v0A.z; aA.w += wgt * v0A.w;
                    aB.x += wgt * v0B.x; aB.y += wgt * v0B.y; aB.z += wgt * v0B.z; aB.w += wgt * v0B.w;

                    v0A = v1A; v0B = v1B;
                    v1A = v2A; v1B = v2B;
                    s2 = s3;
                }

#pragma unroll
                for (int o = 16; o <= 32; o <<= 1) {
                    s += __shfl_xor(s, o, 64);
                    aA.x += __shfl_xor(aA.x, o, 64); aA.y += __shfl_xor(aA.y, o, 64);
                    aA.z += __shfl_xor(aA.z, o, 64); aA.w += __shfl_xor(aA.w, o, 64);
                    aB.x += __shfl_xor(aB.x, o, 64); aB.y += __shfl_xor(aB.y, o, 64);
                    aB.z += __shfl_xor(aB.z, o, 64); aB.w += __shfl_xor(aB.w, o, 64);
                }
                if (sub == 0) {
                    float inv = 1.f / (s + 1e-16f);
                    float4 bA = bias4[2 * cl], bB = bias4[2 * cl + 1];
                    float4 oA, oB;
                    oA.x = aA.x * inv + bA.x; oA.y = aA.y * inv + bA.y;
                    oA.z = aA.z * inv + bA.z; oA.w = aA.w * inv + bA.w;
                    oB.x = aB.x * inv + bB.x; oB.y = aB.y * inv + bB.y;
                    oB.z = aB.z * inv + bB.z; oB.w = aB.w * inv + bB.w;
                    out4[(size_t)i * 32 + 2 * cl] = oA;
                    out4[(size_t)i * 32 + 2 * cl + 1] = oB;
                }
            }
        }
        grid.sync();

        xc = xn;
        xn = (xn == xA) ? xB : xA;
    }

    // ---- head: one row per wave ----
    {
        int chunk = 2 + nch[0];
        float2 wv = ((const float2*)wh)[lane];
        for (int r = gw; r < out_n; r += GW) {
            int row = (r >> 1) * chunk + (r & 1);
            float2 xv = ((const float2*)(xc + (size_t)row * 128))[lane];
            float p = xv.x * wv.x + xv.y * wv.y;
#pragma unroll
            for (int o = 32; o >= 1; o >>= 1) p += __shfl_xor(p, o, 64);
            if (lane == 0) out[r] = p + bh[0];
        }
    }
}

// =================================================================
// Fallback multi-launch path (R5 kernels, proven)
// =================================================================

__global__ void count_kernel(const int* __restrict__ ei, int E, int N, int* __restrict__ deg) {
    int e = blockIdx.x * blockDim.x + threadIdx.x;
    if (e >= E) return;
    int is64 = detect_is64(ei);
    long long pos = (long long)E + e;
    int d = ei[is64 ? 2 * pos : pos];
    if ((unsigned)d < (unsigned)N) atomicAdd(&deg[d], 1);
}

__global__ __launch_bounds__(256) void scan_kernel(const int* __restrict__ deg,
                                                   int* __restrict__ off,
                                                   int* __restrict__ cur, int N) {
    __shared__ int wsum[4];
    int t = threadIdx.x;
    int per = (N + 255) >> 8;
    int b0 = t * per;
    int s = 0;
    for (int k = 0; k < per; k++) {
        int idx = b0 + k;
        if (idx < N) s += deg[idx];
    }
    int lane = t & 63, w = t >> 6;
    int v = s;
#pragma unroll
    for (int o = 1; o < 64; o <<= 1) {
        int u = __shfl_up(v, o, 64);
        if (lane >= o) v += u;
    }
    if (lane == 63) wsum[w] = v;
    __syncthreads();
    if (t == 0) {
        int r = 0;
#pragma unroll
        for (int j = 0; j < 4; j++) { int xx = wsum[j]; wsum[j] = r; r += xx; }
        off[N] = r;
    }
    __syncthreads();
    int run = v - s + wsum[w];
    for (int k = 0; k < per; k++) {
        int idx = b0 + k;
        if (idx < N) {
            off[idx] = run;
            cur[idx] = run;
            run += deg[idx];
        }
    }
}

__global__ void fill_kernel(const int* __restrict__ ei, int E, int N,
                            int* __restrict__ cur, int* __restrict__ esrc) {
    int e = blockIdx.x * blockDim.x + threadIdx.x;
    if (e >= E) return;
    int is64 = detect_is64(ei);
    long long spos = e, dpos = (long long)E + e;
    int s = ei[is64 ? 2 * spos : spos];
    int d = ei[is64 ? 2 * dpos : dpos];
    if ((unsigned)d >= (unsigned)N || (unsigned)s >= (unsigned)N) return;
    int p = atomicAdd(&cur[d], 1);
    esrc[p] = s;
}

__global__ __launch_bounds__(512, 1) void gemm_xlxr(const float* __restrict__ x,
                                                    const float* __restrict__ Wl_,
                                                    const float* __restrict__ blv,
                                                    const float* __restrict__ Wr_,
                                                    const float* __restrict__ brv,
                                                    float* __restrict__ xl,
                                                    float* __restrict__ xr,
                                                    int N, int ntiles) {
    int t = threadIdx.x;
    int w = t >> 6, lane = t & 63, q = lane >> 4, cl = lane & 15;
    bf16x8 Bh[2][4], Bl[2][4];
    float biasv[2];
    float* outp[2];
    int colc[2];
#pragma unroll
    for (int nt = 0; nt < 2; nt++) {
        int col = w * 32 + nt * 16 + cl;
        const float* Wsrc;
        int cw;
        if (col < 128) { Wsrc = Wl_; cw = col; biasv[nt] = blv[col]; outp[nt] = xl; colc[nt] = col; }
        else           { Wsrc = Wr_; cw = col - 128; biasv[nt] = brv[cw]; outp[nt] = xr; colc[nt] = cw; }
#pragma unroll
        for (int kt = 0; kt < 4; kt++) {
            int kb = kt * 32 + q * 8;
            float ftmp[8];
#pragma unroll
            for (int j = 0; j < 8; j++) ftmp[j] = Wsrc[(size_t)(kb + j) * 128 + cw];
            float4 f0 = make_float4(ftmp[0], ftmp[1], ftmp[2], ftmp[3]);
            float4 f1 = make_float4(ftmp[4], ftmp[5], ftmp[6], ftmp[7]);
            cvt8(f0, f1, Bh[nt][kt], Bl[nt][kt]);
        }
    }
    int rt = blockIdx.x;
    if (rt >= ntiles) return;
    float4 cur[8], nxt[8];
    {
        int row = rt * 16 + cl;
        if (row >= N) row = N - 1;
        const float* ap = x + (size_t)row * 128 + q * 8;
#pragma unroll
        for (int kt = 0; kt < 4; kt++) {
            cur[2 * kt]     = *(const float4*)(ap + kt * 32);
            cur[2 * kt + 1] = *(const float4*)(ap + kt * 32 + 4);
        }
    }
    for (; rt < ntiles; rt += gridDim.x) {
        int rn = rt + gridDim.x;
        if (rn < ntiles) {
            int row = rn * 16 + cl;
            if (row >= N) row = N - 1;
            const float* ap = x + (size_t)row * 128 + q * 8;
#pragma unroll
            for (int kt = 0; kt < 4; kt++) {
                nxt[2 * kt]     = *(const float4*)(ap + kt * 32);
                nxt[2 * kt + 1] = *(const float4*)(ap + kt * 32 + 4);
            }
        }
        bf16x8 Ah[4], Al[4];
#pragma unroll
        for (int kt = 0; kt < 4; kt++) cvt8(cur[2 * kt], cur[2 * kt + 1], Ah[kt], Al[kt]);
        f32x4 acc0 = {0.f, 0.f, 0.f, 0.f}, acc1 = {0.f, 0.f, 0.f, 0.f};
#pragma unroll
        for (int kt = 0; kt < 4; kt++) {
            acc0 = __builtin_amdgcn_mfma_f32_16x16x32_bf16(Ah[kt], Bh[0][kt], acc0, 0, 0, 0);
            acc1 = __builtin_amdgcn_mfma_f32_16x16x32_bf16(Ah[kt], Bh[1][kt], acc1, 0, 0, 0);
            acc0 = __builtin_amdgcn_mfma_f32_16x16x32_bf16(Al[kt], Bh[0][kt], acc0, 0, 0, 0);
            acc1 = __builtin_amdgcn_mfma_f32_16x16x32_bf16(Al[kt], Bh[1][kt], acc1, 0, 0, 0);
            acc0 = __builtin_amdgcn_mfma_f32_16x16x32_bf16(Ah[kt], Bl[0][kt], acc0, 0, 0, 0);
            acc1 = __builtin_amdgcn_mfma_f32_16x16x32_bf16(Ah[kt], Bl[1][kt], acc1, 0, 0, 0);
        }
#pragma unroll
        for (int nt = 0; nt < 2; nt++) {
            f32x4 a = nt ? acc1 : acc0;
#pragma unroll
            for (int r = 0; r < 4; r++) {
                int row = rt * 16 + q * 4 + r;
                if (row < N) outp[nt][(size_t)row * 128 + colc[nt]] = a[r] + biasv[nt];
            }
        }
#pragma unroll
        for (int j = 0; j < 8; j++) cur[j] = nxt[j];
    }
}

__global__ __launch_bounds__(256) void gat_agg(const float4* __restrict__ xl4,
                                               const float4* __restrict__ xr4,
                                               const int* __restrict__ off,
                                               const int* __restrict__ esrc,
                                               const float4* __restrict__ att4,
                                               const float4* __restrict__ bias4,
                                               float4* __restrict__ out4, int N) {
    int lane = threadIdx.x & 63;
    int sub = lane >> 4;
    int cl = lane & 15;
    int i = blockIdx.x * 4 + (threadIdx.x >> 6);
    if (i >= N) return;
    float4 xrA = xr4[(size_t)i * 32 + 2 * cl];
    float4 xrB = xr4[(size_t)i * 32 + 2 * cl + 1];
    float4 atA = att4[2 * cl];
    float4 atB = att4[2 * cl + 1];
    int start = off[i];
    int total = off[i + 1] - start + 1;
    int groups = (total + 3) >> 2;
    float s = 0.f;
    float4 aA = make_float4(0.f, 0.f, 0.f, 0.f);
    float4 aB = make_float4(0.f, 0.f, 0.f, 0.f);
    int k = sub;
    int src = (k < total) ? ((k == 0) ? i : esrc[start + k - 1]) : i;
    float4 vA = xl4[(size_t)src * 32 + 2 * cl];
    float4 vB = xl4[(size_t)src * 32 + 2 * cl + 1];
    int valid = (k < total);
    for (int g = 0; g < groups; g++) {
        int kn = 4 * (g + 1) + sub;
        int srcn = (kn < total) ? esrc[start + kn - 1] : i;
        float4 wA = xl4[(size_t)srcn * 32 + 2 * cl];
        float4 wB = xl4[(size_t)srcn * 32 + 2 * cl + 1];
        float z0 = vA.x + xrA.x, z1 = vA.y + xrA.y, z2 = vA.z + xrA.z, z3 = vA.w + xrA.w;
        float z4 = vB.x + xrB.x, z5 = vB.y + xrB.y, z6 = vB.z + xrB.z, z7 = vB.w + xrB.w;
        z0 = (z0 > 0.f) ? z0 : 0.2f * z0;
        z1 = (z1 > 0.f) ? z1 : 0.2f * z1;
        z2 = (z2 > 0.f) ? z2 : 0.2f * z2;
        z3 = (z3 > 0.f) ? z3 : 0.2f * z3;
        z4 = (z4 > 0.f) ? z4 : 0.2f * z4;
        z5 = (z5 > 0.f) ? z5 : 0.2f * z5;
        z6 = (z6 > 0.f) ? z6 : 0.2f * z6;
        z7 = (z7 > 0.f) ? z7 : 0.2f * z7;
        float p = z0 * atA.x + z1 * atA.y + z2 * atA.z + z3 * atA.w
                + z4 * atB.x + z5 * atB.y + z6 * atB.z + z7 * atB.w;
        p += __shfl_xor(p, 1, 64);
        p = fminf(fmaxf(p, -80.f), 80.f);
        float wgt = valid ? __expf(p) : 0.f;
        s += wgt;
        aA.x += wgt * vA.x; aA.y += wgt * vA.y; aA.z += wgt * vA.z; aA.w += wgt * vA.w;
        aB.x += wgt * vB.x; aB.y += wgt * vB.y; aB.z += wgt * vB.z; aB.w += wgt * vB.w;
        vA = wA; vB = wB;
        valid = (kn < total);
    }
#pragma unroll
    for (int o = 16; o <= 32; o <<= 1) {
        s += __shfl_xor(s, o, 64);
        aA.x += __shfl_xor(aA.x, o, 64); aA.y += __shfl_xor(aA.y, o, 64);
        aA.z += __shfl_xor(aA.z, o, 64); aA.w += __shfl_xor(aA.w, o, 64);
        aB.x += __shfl_xor(aB.x, o, 64); aB.y += __shfl_xor(aB.y, o, 64);
        aB.z += __shfl_xor(aB.z, o, 64); aB.w += __shfl_xor(aB.w, o, 64);
    }
    if (sub == 0) {
        float inv = 1.f / (s + 1e-16f);
        float4 bA = bias4[2 * cl], bB = bias4[2 * cl + 1];
        float4 oA, oB;
        oA.x = aA.x * inv + bA.x; oA.y = aA.y * inv + bA.y;
        oA.z = aA.z * inv + bA.z; oA.w = aA.w * inv + bA.w;
        oB.x = aB.x * inv + bB.x; oB.y = aB.y * inv + bB.y;
        oB.z = aB.z * inv + bB.z; oB.w = aB.w * inv + bB.w;
        out4[(size_t)i * 32 + 2 * cl] = oA;
        out4[(size_t)i * 32 + 2 * cl + 1] = oB;
    }
}

__global__ __launch_bounds__(128) void head_kernel(const float* __restrict__ x,
                                                   const float* __restrict__ w,
                                                   const float* __restrict__ bh,
                                                   const int* __restrict__ nch,
                                                   float* __restrict__ out) {
    __shared__ float r[2];
    int b = blockIdx.x, t = threadIdx.x;
    int chunk = 2 + nch[0];
    int row = (b >> 1) * chunk + (b & 1);
    float p = x[(size_t)row * 128 + t] * w[t];
#pragma unroll
    for (int o = 32; o >= 1; o >>= 1) p += __shfl_xor(p, o, 64);
    if ((t & 63) == 0) r[t >> 6] = p;
    __syncthreads();
    if (t == 0) out[b] = r[0] + r[1] + bh[0];
}

// ---------------- launch ----------------

extern "C" void kernel_launch(void* const* d_in, const int* in_sizes, int n_in,
                              void* d_out, int out_size, void* d_ws, size_t ws_size,
                              hipStream_t stream) {
    const float* x0 = (const float*)d_in[0];
    const int* ei = (const int*)d_in[1];
    const int* nchunks = (const int*)d_in[2];
    const float* Wl = (const float*)d_in[3];
    const float* bl = (const float*)d_in[4];
    const float* Wr = (const float*)d_in[5];
    const float* br = (const float*)d_in[6];
    const float* att = (const float*)d_in[7];
    const float* bias = (const float*)d_in[8];
    const float* wh = (const float*)d_in[9];
    const float* bh = (const float*)d_in[10];
    float* outp = (float*)d_out;

    const int D = 128;
    int N = in_sizes[0] / D;   // 10000
    int E = in_sizes[1] / 2;   // 160000
    int ntiles = (N + 15) / 16;

    size_t fN = (size_t)N * D;
    float* xl = (float*)d_ws;
    float* xr = xl + fN;
    float* xA = xr + fN;
    float* xB = xA + fN;
    int* deg = (int*)(xB + fN);
    int* off = deg + N;
    int* cur = off + N + 1;
    int* esrc = cur + N;

    // ---- primary: single cooperative mega-kernel ----
    void* args[] = {
        (void*)&x0, (void*)&ei, (void*)&nchunks,
        (void*)&Wl, (void*)&bl, (void*)&Wr, (void*)&br,
        (void*)&att, (void*)&bias, (void*)&wh, (void*)&bh,
        (void*)&xl, (void*)&xr, (void*)&xA, (void*)&xB,
        (void*)&deg, (void*)&off, (void*)&cur, (void*)&esrc,
        (void*)&outp, (void*)&out_size, (void*)&N, (void*)&E, (void*)&ntiles
    };
    hipError_t rc = hipLaunchCooperativeKernel((void*)gat_mega, dim3(256), dim3(512),
                                               args, 0, stream);
    if (rc == hipSuccess) return;

    // ---- fallback: proven multi-launch path ----
    hipMemsetAsync(deg, 0, (size_t)N * sizeof(int), stream);
    count_kernel<<<(E + NT - 1) / NT, NT, 0, stream>>>(ei, E, N, deg);
    scan_kernel<<<1, 256, 0, stream>>>(deg, off, cur, N);
    fill_kernel<<<(E + NT - 1) / NT, NT, 0, stream>>>(ei, E, N, cur, esrc);

    int aggblocks = (N + 3) / 4;
    const float* xc = x0;
    float* xn = xA;
    for (int l = 0; l < 7; l++) {
        gemm_xlxr<<<256, 512, 0, stream>>>(xc, Wl + (size_t)l * D * D, bl + (size_t)l * D,
                                           Wr + (size_t)l * D * D, br + (size_t)l * D,
                                           xl, xr, N, ntiles);
        gat_agg<<<aggblocks, 256, 0, stream>>>((const float4*)xl, (const float4*)xr, off, esrc,
                                               (const float4*)(att + (size_t)l * D),
                                               (const float4*)(bias + (size_t)l * D),
                                               (float4*)xn, N);
        xc = xn;
        xn = (xn == xA) ? xB : xA;
    }
    head_kernel<<<out_size, 128, 0, stream>>>(xc, wh, bh, nchunks, outp);
}

// Round 7
// 316.624 us; speedup vs baseline: 2.8274x; 2.8274x over previous
//
#include <hip/hip_runtime.h>
#include <math.h>

#define NT 256

typedef __attribute__((ext_vector_type(8))) short bf16x8;
typedef __attribute__((ext_vector_type(4))) float f32x4;

// ---------------- helpers ----------------

__device__ inline int detect_is64(const int* __restrict__ ei) {
    int is64 = 1;
#pragma unroll
    for (int k = 1; k < 16; k += 2) is64 &= (ei[k] == 0);
    return is64;
}

__device__ inline void split1(float f, short& hi, short& lo) {
    unsigned u = __float_as_uint(f);
    hi = (short)(u >> 16);
    float fl = f - __uint_as_float(u & 0xffff0000u);
    lo = (short)(__float_as_uint(fl) >> 16);
}

__device__ inline void cvt8(const float4& a, const float4& b, bf16x8& hi, bf16x8& lo) {
    float f[8] = {a.x, a.y, a.z, a.w, b.x, b.y, b.z, b.w};
#pragma unroll
    for (int j = 0; j < 8; j++) {
        unsigned u = __float_as_uint(f[j]);
        hi[j] = (short)(u >> 16);
        float fl = f[j] - __uint_as_float(u & 0xffff0000u);
        lo[j] = (short)(__float_as_uint(fl) >> 16);
    }
}

// ---------------- CSR build ----------------

__global__ void count_kernel(const int* __restrict__ ei, int E, int N, int* __restrict__ deg) {
    int e = blockIdx.x * blockDim.x + threadIdx.x;
    if (e >= E) return;
    int is64 = detect_is64(ei);
    long long pos = (long long)E + e;
    int d = ei[is64 ? 2 * pos : pos];
    if ((unsigned)d < (unsigned)N) atomicAdd(&deg[d], 1);
}

__global__ __launch_bounds__(256) void scan_kernel(const int* __restrict__ deg,
                                                   int* __restrict__ off,
                                                   int* __restrict__ cur, int N) {
    __shared__ int wsum[4];
    int t = threadIdx.x;
    int per = (N + 255) >> 8;
    int b0 = t * per;
    int s = 0;
    for (int k = 0; k < per; k++) {
        int idx = b0 + k;
        if (idx < N) s += deg[idx];
    }
    int lane = t & 63, w = t >> 6;
    int v = s;
#pragma unroll
    for (int o = 1; o < 64; o <<= 1) {
        int u = __shfl_up(v, o, 64);
        if (lane >= o) v += u;
    }
    if (lane == 63) wsum[w] = v;
    __syncthreads();
    if (t == 0) {
        int r = 0;
#pragma unroll
        for (int j = 0; j < 4; j++) { int xx = wsum[j]; wsum[j] = r; r += xx; }
        off[N] = r;
    }
    __syncthreads();
    int run = v - s + wsum[w];
    for (int k = 0; k < per; k++) {
        int idx = b0 + k;
        if (idx < N) {
            off[idx] = run;
            cur[idx] = run;
            run += deg[idx];
        }
    }
}

__global__ void fill_kernel(const int* __restrict__ ei, int E, int N,
                            int* __restrict__ cur, int* __restrict__ esrc) {
    int e = blockIdx.x * blockDim.x + threadIdx.x;
    if (e >= E) return;
    int is64 = detect_is64(ei);
    long long spos = e, dpos = (long long)E + e;
    int s = ei[is64 ? 2 * spos : spos];
    int d = ei[is64 ? 2 * dpos : dpos];
    if ((unsigned)d >= (unsigned)N || (unsigned)s >= (unsigned)N) return;
    int p = atomicAdd(&cur[d], 1);
    esrc[p] = s;
}

// ---------------- prep_w: transpose W into MFMA B-fragment layout ----------------
// Fragment order: [layer][tile(16)][kt(4)][lane(64)][8 shorts].
// For lane (q=lane>>4, cl=lane&15): value j = W[kt*32+q*8+j][tile*16+cl] (hi/lo bf16 split).
// One block per (layer, tile): stage 128x16 W slice in LDS (coalesced), emit frags.

__global__ __launch_bounds__(256) void prep_w(const float* __restrict__ Wl,
                                              const float* __restrict__ Wr,
                                              short* __restrict__ Whi,
                                              short* __restrict__ Wlo) {
    __shared__ float Wt[128][17];
    int l = blockIdx.x >> 4;
    int tile = blockIdx.x & 15;
    int c0 = tile * 16;
    const float* Wsrc = (c0 < 128) ? Wl + (size_t)l * 16384 : Wr + (size_t)l * 16384;
    int cbase = (c0 < 128) ? c0 : c0 - 128;
    int t = threadIdx.x;
#pragma unroll
    for (int it = 0; it < 8; it++) {
        int idx = it * 256 + t;
        int k = idx >> 4, c = idx & 15;
        Wt[k][c] = Wsrc[(size_t)k * 128 + cbase + c];
    }
    __syncthreads();
    int kt = t >> 6, lane = t & 63, q = (lane >> 4), cl = lane & 15;
    bf16x8 hi, lo;
#pragma unroll
    for (int j = 0; j < 8; j++) {
        short h, lw;
        split1(Wt[kt * 32 + q * 8 + j][cl], h, lw);
        hi[j] = h; lo[j] = lw;
    }
    size_t off = ((((size_t)l * 16 + tile) * 4 + kt) * 64 + lane) * 8;
    *(bf16x8*)(Whi + off) = hi;
    *(bf16x8*)(Wlo + off) = lo;
}

// ---------------- GEMM via bf16x3 MFMA (no LDS, no barriers) ----------------
// B frags loaded coalesced from prepped layout; A streams from global with
// 1-deep row-tile pipeline; fp32 = Ah*Bh + Al*Bh + Ah*Bl.

__global__ __launch_bounds__(512, 1) void gemm_xlxr(const float* __restrict__ x,
                                                    const short* __restrict__ WhiL,
                                                    const short* __restrict__ WloL,
                                                    const float* __restrict__ blv,
                                                    const float* __restrict__ brv,
                                                    float* __restrict__ xl,
                                                    float* __restrict__ xr,
                                                    int N, int ntiles) {
    int t = threadIdx.x;
    int w = t >> 6, lane = t & 63, q = lane >> 4, cl = lane & 15;

    bf16x8 Bh[2][4], Bl[2][4];
    float biasv[2];
    float* outp[2];
    int colc[2];
#pragma unroll
    for (int nt = 0; nt < 2; nt++) {
        int tile = w * 2 + nt;
        int col = tile * 16 + cl;
        if (col < 128) { biasv[nt] = blv[col]; outp[nt] = xl; colc[nt] = col; }
        else           { biasv[nt] = brv[col - 128]; outp[nt] = xr; colc[nt] = col - 128; }
#pragma unroll
        for (int kt = 0; kt < 4; kt++) {
            size_t off = (((size_t)tile * 4 + kt) * 64 + lane) * 8;
            Bh[nt][kt] = *(const bf16x8*)(WhiL + off);
            Bl[nt][kt] = *(const bf16x8*)(WloL + off);
        }
    }

    int rt = blockIdx.x;
    if (rt >= ntiles) return;
    float4 cur[8], nxt[8];
    {
        int row = rt * 16 + cl;
        if (row >= N) row = N - 1;
        const float* ap = x + (size_t)row * 128 + q * 8;
#pragma unroll
        for (int kt = 0; kt < 4; kt++) {
            cur[2 * kt]     = *(const float4*)(ap + kt * 32);
            cur[2 * kt + 1] = *(const float4*)(ap + kt * 32 + 4);
        }
    }

    for (; rt < ntiles; rt += gridDim.x) {
        int rn = rt + gridDim.x;
        if (rn < ntiles) {
            int row = rn * 16 + cl;
            if (row >= N) row = N - 1;
            const float* ap = x + (size_t)row * 128 + q * 8;
#pragma unroll
            for (int kt = 0; kt < 4; kt++) {
                nxt[2 * kt]     = *(const float4*)(ap + kt * 32);
                nxt[2 * kt + 1] = *(const float4*)(ap + kt * 32 + 4);
            }
        }

        bf16x8 Ah[4], Al[4];
#pragma unroll
        for (int kt = 0; kt < 4; kt++) cvt8(cur[2 * kt], cur[2 * kt + 1], Ah[kt], Al[kt]);

        f32x4 acc0 = {0.f, 0.f, 0.f, 0.f}, acc1 = {0.f, 0.f, 0.f, 0.f};
#pragma unroll
        for (int kt = 0; kt < 4; kt++) {
            acc0 = __builtin_amdgcn_mfma_f32_16x16x32_bf16(Ah[kt], Bh[0][kt], acc0, 0, 0, 0);
            acc1 = __builtin_amdgcn_mfma_f32_16x16x32_bf16(Ah[kt], Bh[1][kt], acc1, 0, 0, 0);
            acc0 = __builtin_amdgcn_mfma_f32_16x16x32_bf16(Al[kt], Bh[0][kt], acc0, 0, 0, 0);
            acc1 = __builtin_amdgcn_mfma_f32_16x16x32_bf16(Al[kt], Bh[1][kt], acc1, 0, 0, 0);
            acc0 = __builtin_amdgcn_mfma_f32_16x16x32_bf16(Ah[kt], Bl[0][kt], acc0, 0, 0, 0);
            acc1 = __builtin_amdgcn_mfma_f32_16x16x32_bf16(Ah[kt], Bl[1][kt], acc1, 0, 0, 0);
        }

        // C/D layout: col = lane&15, row = quad*4 + reg  [m89-verified]
#pragma unroll
        for (int nt = 0; nt < 2; nt++) {
            f32x4 a = nt ? acc1 : acc0;
#pragma unroll
            for (int r = 0; r < 4; r++) {
                int row = rt * 16 + q * 4 + r;
                if (row < N) outp[nt][(size_t)row * 128 + colc[nt]] = a[r] + biasv[nt];
            }
        }
#pragma unroll
        for (int j = 0; j < 8; j++) cur[j] = nxt[j];
    }
}

// ---------------- GATv2 aggregation: 4 edges/wave-iter, depth-2/3 prefetch ----------------
// (logic validated in R6 mega run)

__global__ __launch_bounds__(256) void gat_agg(const float4* __restrict__ xl4,
                                               const float4* __restrict__ xr4,
                                               const int* __restrict__ off,
                                               const int* __restrict__ esrc,
                                               const float4* __restrict__ att4,
                                               const float4* __restrict__ bias4,
                                               float4* __restrict__ out4, int N) {
    int lane = threadIdx.x & 63;
    int sub = lane >> 4;
    int cl = lane & 15;
    int i = blockIdx.x * 4 + (threadIdx.x >> 6);
    if (i >= N) return;

    float4 xrA = xr4[(size_t)i * 32 + 2 * cl];
    float4 xrB = xr4[(size_t)i * 32 + 2 * cl + 1];
    float4 atA = att4[2 * cl];
    float4 atB = att4[2 * cl + 1];
    int start = off[i];
    int total = off[i + 1] - start + 1;   // + self-loop at slot 0
    int groups = (total + 3) >> 2;

    int k0 = sub;
    int s0 = (k0 < total) ? ((k0 == 0) ? i : esrc[start + k0 - 1]) : i;
    int k1 = 4 + sub;
    int s1 = (k1 < total) ? esrc[start + k1 - 1] : i;
    float4 v0A = xl4[(size_t)s0 * 32 + 2 * cl];
    float4 v0B = xl4[(size_t)s0 * 32 + 2 * cl + 1];
    int k2 = 8 + sub;
    int s2 = (k2 < total) ? esrc[start + k2 - 1] : i;
    float4 v1A = xl4[(size_t)s1 * 32 + 2 * cl];
    float4 v1B = xl4[(size_t)s1 * 32 + 2 * cl + 1];

    float s = 0.f;
    float4 aA = make_float4(0.f, 0.f, 0.f, 0.f);
    float4 aB = make_float4(0.f, 0.f, 0.f, 0.f);

    for (int g = 0; g < groups; g++) {
        int k3 = 4 * (g + 3) + sub;
        int s3 = (k3 < total) ? esrc[start + k3 - 1] : i;
        float4 v2A = xl4[(size_t)s2 * 32 + 2 * cl];
        float4 v2B = xl4[(size_t)s2 * 32 + 2 * cl + 1];

        int kc = 4 * g + sub;
        int valid = kc < total;
        float z0 = v0A.x + xrA.x, z1 = v0A.y + xrA.y, z2 = v0A.z + xrA.z, z3 = v0A.w + xrA.w;
        float z4 = v0B.x + xrB.x, z5 = v0B.y + xrB.y, z6 = v0B.z + xrB.z, z7 = v0B.w + xrB.w;
        z0 = (z0 > 0.f) ? z0 : 0.2f * z0;
        z1 = (z1 > 0.f) ? z1 : 0.2f * z1;
        z2 = (z2 > 0.f) ? z2 : 0.2f * z2;
        z3 = (z3 > 0.f) ? z3 : 0.2f * z3;
        z4 = (z4 > 0.f) ? z4 : 0.2f * z4;
        z5 = (z5 > 0.f) ? z5 : 0.2f * z5;
        z6 = (z6 > 0.f) ? z6 : 0.2f * z6;
        z7 = (z7 > 0.f) ? z7 : 0.2f * z7;
        float p = z0 * atA.x + z1 * atA.y + z2 * atA.z + z3 * atA.w
                + z4 * atB.x + z5 * atB.y + z6 * atB.z + z7 * atB.w;
        p += __shfl_xor(p, 1, 64);
        p = fminf(fmaxf(p, -80.f), 80.f);
        float wgt = valid ? __expf(p) : 0.f;
        s += wgt;
        aA.x += wgt * v0A.x; aA.y += wgt * v0A.y; aA.z += wgt * v0A.z; aA.w += wgt * v0A.w;
        aB.x += wgt * v0B.x; aB.y += wgt * v0B.y; aB.z += wgt * v0B.z; aB.w += wgt * v0B.w;

        v0A = v1A; v0B = v1B;
        v1A = v2A; v1B = v2B;
        s2 = s3;
    }

#pragma unroll
    for (int o = 16; o <= 32; o <<= 1) {
        s += __shfl_xor(s, o, 64);
        aA.x += __shfl_xor(aA.x, o, 64); aA.y += __shfl_xor(aA.y, o, 64);
        aA.z += __shfl_xor(aA.z, o, 64); aA.w += __shfl_xor(aA.w, o, 64);
        aB.x += __shfl_xor(aB.x, o, 64); aB.y += __shfl_xor(aB.y, o, 64);
        aB.z += __shfl_xor(aB.z, o, 64); aB.w += __shfl_xor(aB.w, o, 64);
    }
    if (sub == 0) {
        float inv = 1.f / (s + 1e-16f);
        float4 bA = bias4[2 * cl], bB = bias4[2 * cl + 1];
        float4 oA, oB;
        oA.x = aA.x * inv + bA.x; oA.y = aA.y * inv + bA.y;
        oA.z = aA.z * inv + bA.z; oA.w = aA.w * inv + bA.w;
        oB.x = aB.x * inv + bB.x; oB.y = aB.y * inv + bB.y;
        oB.z = aB.z * inv + bB.z; oB.w = aB.w * inv + bB.w;
        out4[(size_t)i * 32 + 2 * cl] = oA;
        out4[(size_t)i * 32 + 2 * cl + 1] = oB;
    }
}

// ---------------- head ----------------

__global__ __launch_bounds__(128) void head_kernel(const float* __restrict__ x,
                                                   const float* __restrict__ w,
                                                   const float* __restrict__ bh,
                                                   const int* __restrict__ nch,
                                                   float* __restrict__ out) {
    __shared__ float r[2];
    int b = blockIdx.x, t = threadIdx.x;
    int chunk = 2 + nch[0];
    int row = (b >> 1) * chunk + (b & 1);
    float p = x[(size_t)row * 128 + t] * w[t];
#pragma unroll
    for (int o = 32; o >= 1; o >>= 1) p += __shfl_xor(p, o, 64);
    if ((t & 63) == 0) r[t >> 6] = p;
    __syncthreads();
    if (t == 0) out[b] = r[0] + r[1] + bh[0];
}

// ---------------- launch ----------------

extern "C" void kernel_launch(void* const* d_in, const int* in_sizes, int n_in,
                              void* d_out, int out_size, void* d_ws, size_t ws_size,
                              hipStream_t stream) {
    const float* x0 = (const float*)d_in[0];
    const int* ei = (const int*)d_in[1];
    const int* nchunks = (const int*)d_in[2];
    const float* Wl = (const float*)d_in[3];
    const float* bl = (const float*)d_in[4];
    const float* Wr = (const float*)d_in[5];
    const float* br = (const float*)d_in[6];
    const float* att = (const float*)d_in[7];
    const float* bias = (const float*)d_in[8];
    const float* wh = (const float*)d_in[9];
    const float* bh = (const float*)d_in[10];

    const int D = 128;
    int N = in_sizes[0] / D;   // 10000
    int E = in_sizes[1] / 2;   // 160000
    int ntiles = (N + 15) / 16;

    size_t fN = (size_t)N * D;
    const size_t WFRAG = 16 * 4 * 64 * 8;        // shorts per layer (32768)
    float* xl = (float*)d_ws;
    float* xr = xl + fN;
    float* xA = xr + fN;
    float* xB = xA + fN;
    short* Whi = (short*)(xB + fN);
    short* Wlo = Whi + 7 * WFRAG;
    int* deg = (int*)(Wlo + 7 * WFRAG);
    int* off = deg + N;
    int* cur = off + N + 1;
    int* esrc = cur + N;

    // CSR build + W prep (W prep independent of CSR)
    hipMemsetAsync(deg, 0, (size_t)N * sizeof(int), stream);
    prep_w<<<112, 256, 0, stream>>>(Wl, Wr, Whi, Wlo);
    count_kernel<<<(E + NT - 1) / NT, NT, 0, stream>>>(ei, E, N, deg);
    scan_kernel<<<1, 256, 0, stream>>>(deg, off, cur, N);
    fill_kernel<<<(E + NT - 1) / NT, NT, 0, stream>>>(ei, E, N, cur, esrc);

    int aggblocks = (N + 3) / 4;
    const float* xc = x0;
    float* xn = xA;
    for (int l = 0; l < 7; l++) {
        gemm_xlxr<<<256, 512, 0, stream>>>(xc, Whi + (size_t)l * WFRAG, Wlo + (size_t)l * WFRAG,
                                           bl + (size_t)l * D, br + (size_t)l * D,
                                           xl, xr, N, ntiles);
        gat_agg<<<aggblocks, 256, 0, stream>>>((const float4*)xl, (const float4*)xr, off, esrc,
                                               (const float4*)(att + (size_t)l * D),
                                               (const float4*)(bias + (size_t)l * D),
                                               (float4*)xn, N);
        xc = xn;
        xn = (xn == xA) ? xB : xA;
    }
    head_kernel<<<out_size, 128, 0, stream>>>(xc, wh, bh, nchunks, (float*)d_out);
}